// Round 5
// baseline (62.152 us; speedup 1.0000x reference)
//
#include <hip/hip_runtime.h>
#include <math.h>

#define N_I 1152
#define N_O 10
#define N_D 16
#define BLK 256
#define KPT 18            // i-rows per thread: 1152 / (BLK/4)
#define NITEM 5           // (b,o) items per block
#define ROWS (N_O * N_D)  // 160 floats per i-row

// Persistent ping-pong: grid = 2 blocks per batch element (exactly 2/CU),
// each block routes 5 consecutive o's of one b. Two register tiles uA/uB
// (144 data VGPRs); next item's 18 global_load_dwordx4 are issued BEFORE the
// current item's routing compute, so every block keeps 18KB/wave of HBM
// requests in flight during its VALU-only phases. Only the final item's
// compute (~2us, once) is exposed. launch_bounds(256,2) -> <=256 VGPR,
// 8 waves/CU.
__global__ __launch_bounds__(BLK, 2)
void caps_route(const float* __restrict__ u_hat, float* __restrict__ out)
{
    __shared__ float scr_s[4][16];                // per-wave partial s
    __shared__ float scr_e[4];                    // per-wave partial exp-sum
    __shared__ __align__(16) float vcum[16];      // cumulative v (= logit state)

    const int tid  = threadIdx.x;
    const int wave = tid >> 6;
    const int lane = tid & 63;
    const int d4   = tid & 3;
    const int ig   = tid >> 2;    // 0..63

    const int bid = blockIdx.x;
    const int b   = bid >> 1;
    const int o0  = (bid & 1) * NITEM;

    const float* ptr = u_hat + (size_t)b * (N_I * ROWS) + (size_t)o0 * N_D
                     + (size_t)ig * ROWS + (size_t)d4 * 4;
    float* outb = out + ((size_t)b * N_O + o0) * N_D;

    auto load_tile = [&](float4 (&u)[KPT], int t) {
        const float* g = ptr + t * N_D;
        #pragma unroll
        for (int k = 0; k < KPT; ++k)
            u[k] = *(const float4*)(g + (size_t)(k << 6) * ROWS);
    };

    auto route_item = [&](const float4 (&u)[KPT], int t) {
        if (tid < 16) vcum[tid] = 0.0f;
        float4 vc = make_float4(0.f, 0.f, 0.f, 0.f);
        #pragma unroll
        for (int r = 0; r < 3; ++r) {
            float4 s4 = make_float4(0.f, 0.f, 0.f, 0.f);
            float esum;
            if (r == 0) {
                #pragma unroll
                for (int k = 0; k < KPT; ++k) {
                    s4.x += u[k].x; s4.y += u[k].y;
                    s4.z += u[k].z; s4.w += u[k].w;
                }
                esum = (float)KPT;   // b == 0 -> uniform weights, e_i = 1
            } else {
                esum = 0.0f;
                #pragma unroll
                for (int k = 0; k < KPT; ++k) {
                    float p = u[k].x*vc.x + u[k].y*vc.y
                            + u[k].z*vc.z + u[k].w*vc.w;
                    p += __shfl_xor(p, 1);   // quad butterfly: 16-dim dot
                    p += __shfl_xor(p, 2);
                    const float e = __expf(p);
                    esum += e;
                    s4.x += e*u[k].x; s4.y += e*u[k].y;
                    s4.z += e*u[k].z; s4.w += e*u[k].w;
                }
            }
            // reduce over ig within the wave (lane bits 2..5)
            #pragma unroll
            for (int m = 4; m <= 32; m <<= 1) {
                s4.x += __shfl_xor(s4.x, m);
                s4.y += __shfl_xor(s4.y, m);
                s4.z += __shfl_xor(s4.z, m);
                s4.w += __shfl_xor(s4.w, m);
                esum += __shfl_xor(esum, m);
            }
            if (lane < 4) {
                scr_s[wave][lane*4+0] = s4.x;
                scr_s[wave][lane*4+1] = s4.y;
                scr_s[wave][lane*4+2] = s4.z;
                scr_s[wave][lane*4+3] = s4.w;
                if (lane == 0) scr_e[wave] = esum;
            }
            __syncthreads();
            if (tid < 16) {
                float s = 0.f, et = 0.f;
                #pragma unroll
                for (int w = 0; w < 4; ++w) { s += scr_s[w][tid]; et += scr_e[w]; }
                s /= et;                          // softmax normalization folded
                float sq = s * s;
                sq += __shfl_xor(sq, 1);
                sq += __shfl_xor(sq, 2);
                sq += __shfl_xor(sq, 4);
                sq += __shfl_xor(sq, 8);
                const float nrm = sqrtf(sq);
                const float v = s * (nrm / (1.0f + sq));  // == sq*s/((1+sq)*nrm)
                if (r == 2) outb[t * N_D + tid] = v;
                else        vcum[tid] += v;       // logit state: b_i = u_i . vcum
            }
            __syncthreads();
            if (r < 2) vc = ((const float4*)vcum)[d4];
        }
    };

    float4 uA[KPT], uB[KPT];
    // Static ping-pong schedule: next tile's loads always in flight while
    // routing the current tile. In-order wave issue makes the register WAR
    // (route(uA) before re-load(uA)) safe.
    load_tile(uA, 0);
    load_tile(uB, 1);
    route_item(uA, 0);
    load_tile(uA, 2);
    route_item(uB, 1);
    load_tile(uB, 3);
    route_item(uA, 2);
    load_tile(uA, 4);
    route_item(uB, 3);
    route_item(uA, 4);
}

extern "C" void kernel_launch(void* const* d_in, const int* in_sizes, int n_in,
                              void* d_out, int out_size, void* d_ws, size_t ws_size,
                              hipStream_t stream)
{
    const float* u_hat = (const float*)d_in[0];
    float* out = (float*)d_out;
    const int B = in_sizes[0] / (N_I * N_O * N_D);
    hipLaunchKernelGGL(caps_route, dim3(B * 2), dim3(BLK), 0, stream, u_hat, out);
}

// Round 6
// 42.828 us; speedup vs baseline: 1.4512x; 1.4512x over previous
//
#include <hip/hip_runtime.h>
#include <math.h>

#define N_I 1152
#define N_O 10
#define N_D 16
#define BLK 256
#define KPT 18            // i-rows per thread: 1152 / (BLK/4)
#define ROWS (N_O * N_D)  // 160 floats per i-row
#define GRID 1024         // 4 blocks/CU, persistent-ish: 2-3 items each

__device__ __forceinline__ const float* item_ptr(const float* u_hat, int wid,
                                                 int ig, int d4)
{
    const int b = wid / N_O;
    const int o = wid - b * N_O;
    return u_hat + (size_t)b * (N_I * ROWS) + (size_t)o * N_D
                 + (size_t)ig * ROWS + (size_t)(d4 << 2);
}

// One routing item (b,o) computed from the register tile u[]. If PRE, the
// next item's 18 loads are issued into u[] RIGHT AFTER r2's last use of it
// (single tile, no extra VGPR pressure - round-5 lesson), fenced by
// sched_barrier(0) so they can't be hoisted above r2's compute.
template<bool PRE>
__device__ __forceinline__ void route_item(
    float4 (&u)[KPT], const float* __restrict__ gnext,
    float* __restrict__ outp,
    int tid, int wave, int lane, int d4,
    float (*scr_s)[16], float* scr_e, float* vcum)
{
    if (tid < 16) vcum[tid] = 0.0f;   // safe: barrier at end of prev item
    float4 vc = make_float4(0.f, 0.f, 0.f, 0.f);
    #pragma unroll
    for (int r = 0; r < 3; ++r) {
        float4 s4 = make_float4(0.f, 0.f, 0.f, 0.f);
        float esum;
        if (r == 0) {
            #pragma unroll
            for (int k = 0; k < KPT; ++k) {   // compiler inserts per-k vmcnt
                s4.x += u[k].x; s4.y += u[k].y;
                s4.z += u[k].z; s4.w += u[k].w;
            }
            esum = (float)KPT;    // b == 0 -> uniform weights, e_i = 1
        } else {
            esum = 0.0f;
            #pragma unroll
            for (int k = 0; k < KPT; ++k) {
                float p = u[k].x*vc.x + u[k].y*vc.y + u[k].z*vc.z + u[k].w*vc.w;
                p += __shfl_xor(p, 1);    // quad butterfly: full 16-dim dot
                p += __shfl_xor(p, 2);
                const float e = __expf(p);
                esum += e;
                s4.x += e*u[k].x; s4.y += e*u[k].y;
                s4.z += e*u[k].z; s4.w += e*u[k].w;
            }
        }
        if (PRE && r == 2) {
            // u[] is dead after r2's k-loop: refill it with the next item.
            __builtin_amdgcn_sched_barrier(0);   // don't hoist above r2 compute
            #pragma unroll
            for (int k = 0; k < KPT; ++k)
                u[k] = *(const float4*)(gnext + (size_t)(k << 6) * ROWS);
            __builtin_amdgcn_sched_barrier(0);   // don't sink below
        }
        // reduce over ig within the wave (lane bits 2..5)
        #pragma unroll
        for (int m = 4; m <= 32; m <<= 1) {
            s4.x += __shfl_xor(s4.x, m);
            s4.y += __shfl_xor(s4.y, m);
            s4.z += __shfl_xor(s4.z, m);
            s4.w += __shfl_xor(s4.w, m);
            esum += __shfl_xor(esum, m);
        }
        if (lane < 4) {
            scr_s[wave][lane*4+0] = s4.x;
            scr_s[wave][lane*4+1] = s4.y;
            scr_s[wave][lane*4+2] = s4.z;
            scr_s[wave][lane*4+3] = s4.w;
            if (lane == 0) scr_e[wave] = esum;
        }
        __syncthreads();
        if (tid < 16) {
            float s = 0.f, et = 0.f;
            #pragma unroll
            for (int w = 0; w < 4; ++w) { s += scr_s[w][tid]; et += scr_e[w]; }
            s /= et;                           // softmax normalization folded
            float sq = s * s;
            sq += __shfl_xor(sq, 1);
            sq += __shfl_xor(sq, 2);
            sq += __shfl_xor(sq, 4);
            sq += __shfl_xor(sq, 8);
            const float nrm = sqrtf(sq);
            const float v = s * (nrm / (1.0f + sq));   // == sq*s/((1+sq)*nrm)
            if (r == 2) outp[tid] = v;
            else        vcum[tid] += v;        // logit state: b_i = u_i . vcum
        }
        __syncthreads();
        if (r < 2) vc = ((const float4*)vcum)[d4];
    }
}

// slot mapping: XCD x (= bid&7) owns slots [x*128, x*128+128) -> each XCD's
// 128 resident blocks cover 128 CONTIGUOUS wids per generation (keeps the
// cross-o L2 line dedup). Third-generation items (512 of them) are spread
// 64 per XCD to avoid a half-chip tail.
__global__ __launch_bounds__(BLK, 4)
void caps_route(const float* __restrict__ u_hat, float* __restrict__ out,
                int items)
{
    __shared__ float scr_s[4][16];
    __shared__ float scr_e[4];
    __shared__ __align__(16) float vcum[16];

    const int tid  = threadIdx.x;
    const int wave = tid >> 6;
    const int lane = tid & 63;
    const int d4   = tid & 3;
    const int ig   = tid >> 2;    // 0..63

    const int bid  = blockIdx.x;
    const int slot = (bid & 7) * (GRID >> 3) + (bid >> 3);

    const int rem    = items - 2 * GRID;              // 512 for B=256
    const int rpx    = rem >> 3;                      // extra items per XCD
    const int within = slot & ((GRID >> 3) - 1);      // 0..127
    const bool extra = within < rpx;
    const int wid3   = 2 * GRID + (slot >> 7) * rpx + within;

    int wid = slot;
    const float* g0 = item_ptr(u_hat, wid, ig, d4);
    float4 u[KPT];
    #pragma unroll
    for (int k = 0; k < KPT; ++k)
        u[k] = *(const float4*)(g0 + (size_t)(k << 6) * ROWS);

    // item 0 (prefetch item 1)
    route_item<true>(u, item_ptr(u_hat, slot + GRID, ig, d4),
                     out + (size_t)wid * N_D, tid, wave, lane, d4,
                     scr_s, scr_e, vcum);
    wid = slot + GRID;
    if (extra) {
        // item 1 (prefetch item 2), then item 2 plain
        route_item<true>(u, item_ptr(u_hat, wid3, ig, d4),
                         out + (size_t)wid * N_D, tid, wave, lane, d4,
                         scr_s, scr_e, vcum);
        route_item<false>(u, (const float*)0,
                          out + (size_t)wid3 * N_D, tid, wave, lane, d4,
                          scr_s, scr_e, vcum);
    } else {
        // item 1 plain
        route_item<false>(u, (const float*)0,
                          out + (size_t)wid * N_D, tid, wave, lane, d4,
                          scr_s, scr_e, vcum);
    }
}

extern "C" void kernel_launch(void* const* d_in, const int* in_sizes, int n_in,
                              void* d_out, int out_size, void* d_ws, size_t ws_size,
                              hipStream_t stream)
{
    const float* u_hat = (const float*)d_in[0];
    float* out = (float*)d_out;
    const int B = in_sizes[0] / (N_I * N_O * N_D);
    const int items = B * N_O;   // 2560 for B=256
    hipLaunchKernelGGL(caps_route, dim3(GRID), dim3(BLK), 0, stream,
                       u_hat, out, items);
}

// Round 7
// 35.991 us; speedup vs baseline: 1.7268x; 1.1900x over previous
//
#include <hip/hip_runtime.h>
#include <math.h>

#define N_I 1152
#define N_O 10
#define N_D 16
#define BLK 512
#define KPT 18            // i-rows per lane-group: 1152 / 64
#define ROWS (N_O * N_D)  // 160 floats per i-row

// One block per (b, o-PAIR), o0 = 2*pair. Thread layout: dquad = t&3
// (d = 4*dquad..), osub = (t>>2)&1 (which o of the pair), irow = t>>3
// (i = irow + 64j). A wave's 16B/lane load covers 8 FULL 128B-aligned L2
// lines (row start i*640 + o0*64 is 128B-aligned for even o0) -> every
// fetched byte is consumed by THIS block; no cross-block dedup dependence.
// 72 data VGPRs/thread; launch_bounds(512,2) -> 128-VGPR cap (round-3 fix),
// 2 blocks/CU = 16 waves. One-shot grid of B*5 blocks for dynamic balance.
__global__ __launch_bounds__(BLK, 2)
void caps_route(const float* __restrict__ u_hat, float* __restrict__ out)
{
    __shared__ float scr_s[8][2][16];             // per-wave, per-osub partial s
    __shared__ float scr_e[8][2];                 // per-wave, per-osub exp-sum
    __shared__ __align__(16) float vcum[2][16];   // per-osub cumulative v

    const int tid   = threadIdx.x;
    const int wave  = tid >> 6;
    const int lane  = tid & 63;
    const int dquad = tid & 3;
    const int osub  = (tid >> 2) & 1;
    const int irow  = tid >> 3;   // 0..63

    // XCD swizzle: 160 consecutive (b,pair) wids per XCD.
    const int bid = blockIdx.x;
    const int nwg = gridDim.x;
    int wid = bid;
    if ((nwg & 7) == 0) wid = (bid & 7) * (nwg >> 3) + (bid >> 3);
    const int b    = wid / 5;
    const int pair = wid - b * 5;

    const float* gptr = u_hat + (size_t)b * (N_I * ROWS)
                      + (size_t)irow * ROWS
                      + (pair << 5) + (osub << 4) + (dquad << 2);

    // ---- global -> registers: 18 x 16B per thread, full-line coalesced ----
    float4 u[KPT];
    float4 s4 = make_float4(0.f, 0.f, 0.f, 0.f);
    #pragma unroll
    for (int k = 0; k < KPT; ++k) {
        u[k] = *(const float4*)(gptr + (size_t)(k << 6) * ROWS);
        s4.x += u[k].x; s4.y += u[k].y;   // r=0 partial sum under vmcnt
        s4.z += u[k].z; s4.w += u[k].w;
    }
    if (tid < 32) vcum[tid >> 4][tid & 15] = 0.0f;

    float4 vc = make_float4(0.f, 0.f, 0.f, 0.f);

    for (int r = 0; r < 3; ++r) {
        float esum;
        if (r == 0) {
            esum = (float)KPT;            // b == 0 -> uniform weights, e_i = 1
        } else {
            s4 = make_float4(0.f, 0.f, 0.f, 0.f);
            esum = 0.0f;
            #pragma unroll
            for (int k = 0; k < KPT; ++k) {
                float p = u[k].x*vc.x + u[k].y*vc.y + u[k].z*vc.z + u[k].w*vc.w;
                p += __shfl_xor(p, 1);    // quad butterfly: full 16-dim dot
                p += __shfl_xor(p, 2);
                const float e = __expf(p);
                esum += e;
                s4.x += e*u[k].x; s4.y += e*u[k].y;
                s4.z += e*u[k].z; s4.w += e*u[k].w;
            }
        }
        // reduce over the 8 irows within the wave (lane bits 3..5)
        #pragma unroll
        for (int m = 8; m <= 32; m <<= 1) {
            s4.x += __shfl_xor(s4.x, m);
            s4.y += __shfl_xor(s4.y, m);
            s4.z += __shfl_xor(s4.z, m);
            s4.w += __shfl_xor(s4.w, m);
            esum += __shfl_xor(esum, m);
        }
        if (lane < 8) {                   // lanes 0..7 = (osub, dquad) combos
            scr_s[wave][lane >> 2][(lane & 3)*4 + 0] = s4.x;
            scr_s[wave][lane >> 2][(lane & 3)*4 + 1] = s4.y;
            scr_s[wave][lane >> 2][(lane & 3)*4 + 2] = s4.z;
            scr_s[wave][lane >> 2][(lane & 3)*4 + 3] = s4.w;
            if ((lane & 3) == 0) scr_e[wave][lane >> 2] = esum;
        }
        __syncthreads();
        if (tid < 32) {                   // lanes 0-15: osub0, 16-31: osub1
            const int j = tid >> 4;
            const int d = tid & 15;
            float s = 0.f, et = 0.f;
            #pragma unroll
            for (int w = 0; w < 8; ++w) { s += scr_s[w][j][d]; et += scr_e[w][j]; }
            s /= et;                      // softmax normalization folded
            float sq = s * s;
            sq += __shfl_xor(sq, 1);      // stays within 16-lane group
            sq += __shfl_xor(sq, 2);
            sq += __shfl_xor(sq, 4);
            sq += __shfl_xor(sq, 8);
            const float nrm = sqrtf(sq);
            const float v = s * (nrm / (1.0f + sq));   // == sq*s/((1+sq)*nrm)
            if (r == 2) out[((size_t)b * N_O + (pair << 1) + j) * N_D + d] = v;
            else        vcum[j][d] += v;  // logit state: b_i = u_i . vcum
        }
        __syncthreads();
        if (r < 2) vc = *(const float4*)&vcum[osub][dquad << 2];
    }
}

extern "C" void kernel_launch(void* const* d_in, const int* in_sizes, int n_in,
                              void* d_out, int out_size, void* d_ws, size_t ws_size,
                              hipStream_t stream)
{
    const float* u_hat = (const float*)d_in[0];
    float* out = (float*)d_out;
    const int B = in_sizes[0] / (N_I * N_O * N_D);
    hipLaunchKernelGGL(caps_route, dim3(B * 5), dim3(BLK), 0, stream, u_hat, out);
}